// Round 1
// baseline (385.188 us; speedup 1.0000x reference)
//
#include <hip/hip_runtime.h>
#include <math.h>

// DeepSeek-V3 MoE gate on gfx950.
// Round 5: kill the per-tile vmcnt(0) barrier drain. Round 3/4 capped at
// MfmaUtil ~26% because __syncthreads() lowers to s_waitcnt vmcnt(0), which
// drains the B(kt+1)/X(kt+2) prefetches issued in the SAME tile body -> one
// exposed HBM latency (~900 cyc) per K-tile. Fix (T4, counted waits):
//   - raw s_barrier + manual lgkmcnt(0) only (LDS visibility is all the
//     barrier must guarantee; global prefetches stay in flight)
//   - K-loop unrolled by 2 with statically named B double-buffer regs
//     (no bcur<-bnext copy, no early vmcnt wait)
//   - two named X prefetch reg sets at distance ~2 tile bodies (~2000 cyc
//     in flight >> 900 cyc HBM latency)
// Numerics unchanged: fp16 hi + 2^11-scaled lo split, 3 MFMAs per logical.

#define N_EXPERTS 256
#define TOPK_GROUP 4
#define TOP_K 8

#define KDIM 7168
#define BM 64
#define BK 32
#define NCHUNK 4
#define KC (KDIM / NCHUNK)        // 1792
#define KTILES (KC / BK)          // 56 k-tiles per chunk (even, needed for unroll-2)
// Wb blob: [tile][w 0..3][plane 0..1][j 0..3][l4 0..3][l16 0..15][jj 0..7] f16
// -> per (tile,w,plane,j): 1KB read by 64 lanes as contiguous dwordx4 (l*8 shorts)
#define TILE_SHORTS 16384
#define LO_SCALE 2048.0f
#define LO_INV (1.0f / 2048.0f)

typedef _Float16 f16x8 __attribute__((ext_vector_type(8)));  // 8 f16 (4 VGPRs)
typedef float f32x4 __attribute__((ext_vector_type(4)));

// W [256][7168] fp32 -> swizzled hi/lo f16 blob (see layout above)
__global__ __launch_bounds__(256)
void convert_w(const float* __restrict__ W, unsigned short* __restrict__ Wb) {
    int g = blockIdx.x * 256 + threadIdx.x;  // n * (KDIM/8) + k8
    int n = g / (KDIM / 8);
    int k8 = g % (KDIM / 8);
    const float* src = W + (long)n * KDIM + k8 * 8;
    float4 v0 = *(const float4*)src;
    float4 v1 = *(const float4*)(src + 4);
    float x[8] = {v0.x, v0.y, v0.z, v0.w, v1.x, v1.y, v1.z, v1.w};
    f16x8 hv, lv;
#pragma unroll
    for (int j = 0; j < 8; ++j) {
        _Float16 h = (_Float16)x[j];
        hv[j] = h;
        lv[j] = (_Float16)((x[j] - (float)h) * LO_SCALE);  // exact split, *2^11 exact
    }
    int tk = k8 >> 2, l4 = k8 & 3;
    int w = n >> 6, j = (n >> 4) & 3, l16 = n & 15;
    unsigned short* d = Wb + (long)tk * TILE_SHORTS + w * 4096 + j * 512 + l4 * 128 + l16 * 8;
    *(f16x8*)d = hv;            // plane 0 (hi)
    *(f16x8*)(d + 2048) = lv;   // plane 1 (lo), +pl stride 4*4*128
}

// One tile body of the software pipeline.
//  CUR_/NXT_: As buffer parity (compile-time constants via unroll-2)
//  BCUR_/BNXT_: statically named B register sets
//  XA_/XB_: the X prefetch reg set whose tile parity matches tile T_+1
#define GEMM_BODY(T_, CUR_, NXT_, BCUR_, BNXT_, XA_, XB_)                            \
    {                                                                                \
        const int t_ = (T_);                                                         \
        /* A fragments for tile t_ first: ds_read latency hides under staging */     \
        f16x8 ah[4], al[4];                                                          \
        _Pragma("unroll")                                                            \
        for (int i = 0; i < 4; ++i) {                                                \
            const char* pa_ =                                                        \
                (const char*)&As[CUR_][0][0] + (i * 16 + l16) * 80 + l4 * 16;        \
            ah[i] = *(const f16x8*)pa_;                                              \
            al[i] = *(const f16x8*)(pa_ + 5120);                                     \
        }                                                                            \
        if (t_ + 1 < KTILES) {                                                       \
            /* stage A(t_+1): regs were loaded ~2 bodies ago -> vmcnt wait ~0 */     \
            float xv[8] = {XA_.x, XA_.y, XA_.z, XA_.w, XB_.x, XB_.y, XB_.z, XB_.w};  \
            f16x8 hv, lv;                                                            \
            _Pragma("unroll")                                                        \
            for (int j = 0; j < 8; ++j) {                                            \
                _Float16 h = (_Float16)xv[j];                                        \
                hv[j] = h;                                                           \
                lv[j] = (_Float16)((xv[j] - (float)h) * LO_SCALE);                   \
            }                                                                        \
            *(f16x8*)&As[NXT_][0][sm * 40 + skq * 8] = hv;                           \
            *(f16x8*)&As[NXT_][1][sm * 40 + skq * 8] = lv;                           \
            /* reload this X set with tile t_+3 (in flight ~2 bodies) */             \
            const int kn_ = (t_ + 3 < KTILES) ? t_ + 3 : KTILES - 1;                 \
            XA_ = *(const float4*)(Xp + kn_ * BK);                                   \
            XB_ = *(const float4*)(Xp + kn_ * BK + 4);                               \
            /* B(t_+1) -> other reg set (L2-resident, 1 body in flight) */           \
            const unsigned short* bp_ = Bp + (long)(t_ + 1) * TILE_SHORTS;           \
            _Pragma("unroll")                                                        \
            for (int pl = 0; pl < 2; ++pl)                                           \
                _Pragma("unroll")                                                    \
                for (int j = 0; j < 4; ++j)                                          \
                    BNXT_[pl * 4 + j] = *(const f16x8*)(bp_ + pl * 2048 + j * 512);  \
        }                                                                            \
        _Pragma("unroll")                                                            \
        for (int i = 0; i < 4; ++i)                                                  \
            _Pragma("unroll")                                                        \
            for (int j = 0; j < 4; ++j) {                                            \
                acc1[i][j] = __builtin_amdgcn_mfma_f32_16x16x32_f16(                 \
                    ah[i], BCUR_[4 + j], acc1[i][j], 0, 0, 0);                       \
                acc1[i][j] = __builtin_amdgcn_mfma_f32_16x16x32_f16(                 \
                    al[i], BCUR_[j], acc1[i][j], 0, 0, 0);                           \
                acc0[i][j] = __builtin_amdgcn_mfma_f32_16x16x32_f16(                 \
                    ah[i], BCUR_[j], acc0[i][j], 0, 0, 0);                           \
            }                                                                        \
        if (t_ + 1 < KTILES) {                                                       \
            /* publish As[NXT_] only: NO vmcnt drain -> prefetches keep flying */    \
            asm volatile("s_waitcnt lgkmcnt(0)" ::: "memory");                       \
            __builtin_amdgcn_s_barrier();                                            \
        }                                                                            \
    }

__global__ __launch_bounds__(256, 2)
void gemm_mfma(const float* __restrict__ X, const unsigned short* __restrict__ Wb,
               float* __restrict__ part, int T) {
    // A double-buffered: [buf][plane][m 0..63][40 f16] (pad 32->40), 20 KB total
    __shared__ __align__(16) unsigned short As[2][2][64 * 40];

    const int tid = threadIdx.x;
    // XCD swizzle: chunk kc owns XCDs {2kc,2kc+1} -> its 1.8MB Wb slice L2-resident
    const int lin = blockIdx.x;
    const int xcd = lin & 7;
    const int kc = xcd >> 1;
    const int mb = ((lin >> 3) << 1) | (xcd & 1);
    const int m0 = mb * BM;

    const int w = tid >> 6;          // wave 0..3 -> n-range w*64
    const int l = tid & 63;
    const int l16 = l & 15, l4 = l >> 4;

    // A staging: thread (m = tid>>2, kq = tid&3) loads 8 consecutive k floats
    const int sm = tid >> 2, skq = tid & 3;
    const float* Xp = X + (long)(m0 + sm) * KDIM + kc * KC + skq * 8;

    // B: per-lane base; tile kt frag (pl,j) at +kt*TILE_SHORTS + pl*2048 + j*512
    const unsigned short* Bp = Wb + (long)(kc * KTILES) * TILE_SHORTS + w * 4096 + l * 8;

    f32x4 acc0[4][4], acc1[4][4];
#pragma unroll
    for (int i = 0; i < 4; ++i)
#pragma unroll
        for (int j = 0; j < 4; ++j) {
            acc0[i][j] = (f32x4){0.f, 0.f, 0.f, 0.f};
            acc1[i][j] = (f32x4){0.f, 0.f, 0.f, 0.f};
        }

    // ---- prologue ----
    {
        // tile 0 -> As[0]
        float4 a0 = *(const float4*)Xp;
        float4 a1 = *(const float4*)(Xp + 4);
        float xv[8] = {a0.x, a0.y, a0.z, a0.w, a1.x, a1.y, a1.z, a1.w};
        f16x8 hv, lv;
#pragma unroll
        for (int j = 0; j < 8; ++j) {
            _Float16 h = (_Float16)xv[j];
            hv[j] = h;
            lv[j] = (_Float16)((xv[j] - (float)h) * LO_SCALE);
        }
        *(f16x8*)&As[0][0][sm * 40 + skq * 8] = hv;
        *(f16x8*)&As[0][1][sm * 40 + skq * 8] = lv;
    }
    // X prefetch sets: xO holds odd tiles (starts at tile 1), xE even (tile 2)
    float4 xO_a = *(const float4*)(Xp + 1 * BK);
    float4 xO_b = *(const float4*)(Xp + 1 * BK + 4);
    float4 xE_a = *(const float4*)(Xp + 2 * BK);
    float4 xE_b = *(const float4*)(Xp + 2 * BK + 4);
    // B double-buffer regs; bb0 <- B(0)
    f16x8 bb0[8], bb1[8];
#pragma unroll
    for (int pl = 0; pl < 2; ++pl)
#pragma unroll
        for (int j = 0; j < 4; ++j)
            bb0[pl * 4 + j] = *(const f16x8*)(Bp + pl * 2048 + j * 512);

    asm volatile("s_waitcnt lgkmcnt(0)" ::: "memory");
    __builtin_amdgcn_s_barrier();

#pragma unroll 1
    for (int kt = 0; kt < KTILES; kt += 2) {
        GEMM_BODY(kt,     0, 1, bb0, bb1, xO_a, xO_b)   // even tile: consumes X(kt+1) [odd set]
        GEMM_BODY(kt + 1, 1, 0, bb1, bb0, xE_a, xE_b)   // odd tile:  consumes X(kt+2) [even set]
    }

    // epilogue: part[kc][m0+m][n]  (C/D layout: col=lane&15, row=(lane>>4)*4+reg)
    float* P = part + ((long)kc * T + m0) * N_EXPERTS;
#pragma unroll
    for (int i = 0; i < 4; ++i) {
        int m = i * 16 + l4 * 4;
        int n = w * 64 + l16;
#pragma unroll
        for (int j = 0; j < 4; ++j)
#pragma unroll
            for (int r = 0; r < 4; ++r)
                P[(long)(m + r) * N_EXPERTS + n + j * 16] =
                    acc0[i][j][r] + acc1[i][j][r] * LO_INV;
    }
}

// One wave (64 lanes) per token; lane l owns experts 4l..4l+3 (group = l>>3).
__global__ __launch_bounds__(256)
void routing_kernel(const float* __restrict__ part, const float* __restrict__ bias,
                    float* __restrict__ out, int T) {
    const int lane = threadIdx.x & 63;
    const int wv = threadIdx.x >> 6;
    const int t = blockIdx.x * 4 + wv;
    if (t >= T) return;
    const long TN = (long)T * N_EXPERTS;

    const float* p = part + (long)t * N_EXPERTS + lane * 4;
    float lg[4] = {0.f, 0.f, 0.f, 0.f};
#pragma unroll
    for (int c = 0; c < NCHUNK; ++c) {
        float4 v = *(const float4*)(p + c * TN);
        lg[0] += v.x; lg[1] += v.y; lg[2] += v.z; lg[3] += v.w;
    }
    float4 bv = *(const float4*)(bias + lane * 4);
    const float bb[4] = {bv.x, bv.y, bv.z, bv.w};

    float s[4], sc[4];
#pragma unroll
    for (int j = 0; j < 4; ++j) {
        s[j] = 1.f / (1.f + expf(-lg[j]));
        sc[j] = s[j] + bb[j];
    }

    // group score = sum of top-2 biased scores within the 32-expert group
    float m1 = fmaxf(sc[0], sc[1]), m2 = fminf(sc[0], sc[1]);
    if (sc[2] > m1) { m2 = m1; m1 = sc[2]; } else m2 = fmaxf(m2, sc[2]);
    if (sc[3] > m1) { m2 = m1; m1 = sc[3]; } else m2 = fmaxf(m2, sc[3]);
#pragma unroll
    for (int o = 1; o <= 4; o <<= 1) {
        float o1 = __shfl_xor(m1, o);
        float o2 = __shfl_xor(m2, o);
        float n1 = fmaxf(m1, o1);
        float n2 = fmaxf(fminf(m1, o1), fmaxf(m2, o2));
        m1 = n1; m2 = n2;
    }
    float gsum = m1 + m2;

    float gs[8];
#pragma unroll
    for (int g = 0; g < 8; ++g) gs[g] = __shfl(gsum, g * 8);

    int selmask = 0;
#pragma unroll
    for (int g = 0; g < 8; ++g) {
        int rank = 0;
#pragma unroll
        for (int h = 0; h < 8; ++h)
            rank += (gs[h] > gs[g]) || (gs[h] == gs[g] && h < g);
        if (rank < TOPK_GROUP) selmask |= 1 << g;
    }

    const int mygrp = lane >> 3;
    float val[4];
#pragma unroll
    for (int j = 0; j < 4; ++j)
        val[j] = ((selmask >> mygrp) & 1) ? sc[j] : -INFINITY;

    float wsel[TOP_K];
    int isel[TOP_K];
    float denom = 1e-20f;
#pragma unroll
    for (int it = 0; it < TOP_K; ++it) {
        float bvv = val[0];
        int bi = lane * 4;
#pragma unroll
        for (int j = 1; j < 4; ++j)
            if (val[j] > bvv) { bvv = val[j]; bi = lane * 4 + j; }
#pragma unroll
        for (int o = 1; o < 64; o <<= 1) {
            float ov = __shfl_xor(bvv, o);
            int oi = __shfl_xor(bi, o);
            if (ov > bvv || (ov == bvv && oi < bi)) { bvv = ov; bi = oi; }
        }
        isel[it] = bi;
        int q = bi & 3, ol = bi >> 2;
        float sv = (q == 0) ? s[0] : (q == 1) ? s[1] : (q == 2) ? s[2] : s[3];
        float w = __shfl(sv, ol);
        wsel[it] = w;
        denom += w;
        if (lane == ol) {
            if (q == 0) val[0] = -INFINITY;
            else if (q == 1) val[1] = -INFINITY;
            else if (q == 2) val[2] = -INFINITY;
            else val[3] = -INFINITY;
        }
    }

    if (lane == 0) {
        float scale = 2.5f / denom;
        long base = (long)t * TOP_K;
        long wbase = (long)T * TOP_K + base;
#pragma unroll
        for (int it = 0; it < TOP_K; ++it) {
            out[base + it] = (float)isel[it];
            out[wbase + it] = wsel[it] * scale;
        }
    }
}

extern "C" void kernel_launch(void* const* d_in, const int* in_sizes, int n_in,
                              void* d_out, int out_size, void* d_ws, size_t ws_size,
                              hipStream_t stream) {
    const float* X = (const float*)d_in[0];     // [T, 7168] fp32
    const float* W = (const float*)d_in[1];     // [256, 7168] fp32
    const float* bias = (const float*)d_in[2];  // [256] fp32
    float* out = (float*)d_out;

    const int K = in_sizes[1] / N_EXPERTS;  // 7168
    const int T = in_sizes[0] / K;          // 8192

    float* part = (float*)d_ws;                                    // 32 MB
    unsigned short* Wb = (unsigned short*)((char*)d_ws + (size_t)NCHUNK * T * N_EXPERTS * 4);  // 7.34 MB

    convert_w<<<(N_EXPERTS * (KDIM / 8)) / 256, 256, 0, stream>>>(W, Wb);
    gemm_mfma<<<(T / BM) * NCHUNK, 256, 0, stream>>>(X, Wb, part, T);
    routing_kernel<<<T / 4, 256, 0, stream>>>(part, bias, out, T);
}